// Round 1
// baseline (285.261 us; speedup 1.0000x reference)
//
#include <hip/hip_runtime.h>

#define TILE 16
#define R    15
#define KW   31
#define NP   32
#define HH   512
#define WW   512
#define NB   4
#define EXT  (TILE + 2*R)      // 46
#define TSTRIDE 48             // row stride: 16*r mod 32 -> exact 2-way bank aliasing (free on wave64)

__global__ __launch_bounds__(256) void defocus_kernel(
    const float* __restrict__ sharp, const float* __restrict__ coc_map,
    float* __restrict__ out)
{
    // weights transposed: gT[tap][plane] so per-lane 'plane' hits distinct banks
    __shared__ float gT[KW][NP];
    __shared__ float bnd[KW];
    __shared__ float tile[3][EXT][TSTRIDE];

    const int tid = threadIdx.x;

    // ---- build per-plane 1-D Gaussian weights (zero-padded to 31, centered at R) ----
    if (tid < NP) {
        const int p = tid;
        const double step = 50.0 / 31.0;
        const float pv = (p == 31) ? 50.0f : (float)((double)p * step);
        #pragma unroll
        for (int j = 0; j < KW; ++j) gT[j][p] = 0.0f;
        if (pv < 0.5f) {
            gT[R][p] = 1.0f;                       // identity plane (plane 0)
        } else {
            const double coc   = (double)pv;
            const double sigma = coc / 2.355;
            int k = (int)(2.0 * coc + 1.0);
            if ((k & 1) == 0) k += 1;
            if (k > KW) k = KW;
            const int half = k >> 1;
            float s = 0.0f;
            for (int j = 0; j < k; ++j) {
                double c = (double)(j - half);
                s += (float)exp(-(c * c) / (2.0 * sigma * sigma));
            }
            for (int j = 0; j < k; ++j) {
                double c = (double)(j - half);
                gT[R - half + j][p] = (float)exp(-(c * c) / (2.0 * sigma * sigma)) / s;
            }
        }
    }
    // ---- bucket boundaries, bit-exact replica of float32((planes[i]+planes[i+1])/2) ----
    if (tid < KW) {
        const double step = 50.0 / 31.0;
        const float pa = (float)((double)tid * step);
        const float pb = (tid == 30) ? 50.0f : (float)((double)(tid + 1) * step);
        bnd[tid] = (pa + pb) * 0.5f;
    }

    // ---- stage input tile (+halo) to LDS, zero padding outside the image ----
    const int bx = blockIdx.x, by = blockIdx.y, bb = blockIdx.z;
    const int x0 = bx * TILE - R, y0 = by * TILE - R;
    for (int idx = tid; idx < EXT * EXT; idx += 256) {
        const int r = idx / EXT, c = idx - r * EXT;
        const int gy = y0 + r, gx = x0 + c;
        const bool ok = ((unsigned)gy < HH) && ((unsigned)gx < WW);
        #pragma unroll
        for (int ch = 0; ch < 3; ++ch) {
            tile[ch][r][c] = ok ? sharp[(((size_t)bb * 3 + ch) * HH + gy) * WW + gx] : 0.0f;
        }
    }
    __syncthreads();

    // ---- per-pixel plane selection (exact reference semantics: count coc > b[j]) ----
    const int tx = tid & (TILE - 1), ty = tid >> 4;
    const int ox = bx * TILE + tx, oy = by * TILE + ty;
    const float coc = coc_map[((size_t)bb * HH + oy) * WW + ox];
    int plane = 0;
    #pragma unroll
    for (int j = 0; j < KW; ++j) plane += (coc > bnd[j]) ? 1 : 0;

    // hoist this pixel's 1-D weights into registers (used for both x and y taps)
    float gv[KW];
    #pragma unroll
    for (int j = 0; j < KW; ++j) gv[j] = gT[j][plane];

    // ---- separable 31x31 accumulation over the LDS tile ----
    float a0 = 0.f, a1 = 0.f, a2 = 0.f;
    for (int dy = 0; dy < KW; ++dy) {
        const float wy = gT[dy][plane];
        const float* p0 = &tile[0][ty + dy][tx];
        const float* p1 = &tile[1][ty + dy][tx];
        const float* p2 = &tile[2][ty + dy][tx];
        float r0 = 0.f, r1 = 0.f, r2 = 0.f;
        #pragma unroll
        for (int dx = 0; dx < KW; ++dx) {
            const float wx = gv[dx];
            r0 = fmaf(wx, p0[dx], r0);
            r1 = fmaf(wx, p1[dx], r1);
            r2 = fmaf(wx, p2[dx], r2);
        }
        a0 = fmaf(wy, r0, a0);
        a1 = fmaf(wy, r1, a1);
        a2 = fmaf(wy, r2, a2);
    }

    const size_t obase = (((size_t)bb * 3) * HH + oy) * WW + ox;
    out[obase]                        = a0;
    out[obase + (size_t)HH * WW]      = a1;
    out[obase + 2 * (size_t)HH * WW]  = a2;
}

extern "C" void kernel_launch(void* const* d_in, const int* in_sizes, int n_in,
                              void* d_out, int out_size, void* d_ws, size_t ws_size,
                              hipStream_t stream) {
    const float* sharp = (const float*)d_in[0];
    const float* coc   = (const float*)d_in[1];
    float* out         = (float*)d_out;
    dim3 grid(WW / TILE, HH / TILE, NB);
    defocus_kernel<<<grid, dim3(256), 0, stream>>>(sharp, coc, out);
}